// Round 8
// baseline (517.579 us; speedup 1.0000x reference)
//
#include <hip/hip_runtime.h>
#include <hip/hip_bf16.h>
#include <cstdint>

#define DI __device__ __forceinline__

using bf16x8 = __attribute__((ext_vector_type(8))) short;
using f32x4  = __attribute__((ext_vector_type(4))) float;

constexpr int IN_DIM = 384;
constexpr int HID    = 512;
constexpr int KTOT   = IN_DIM * 20;          // 7680: k = i*20 + t
constexpr int BM = 256, BN = 128, BK = 160;  // 8 input dims per K-step
constexpr int NSTEP = KTOT / BK;             // 48
// A: row-major, 336B stride (mod 128 = 80): 16-lane b128 read phases cycle all 8 slots
//    (conflict-free, proven R4/R7). Writes: 5 x ds_write_b64 per task, deterministic banks.
// B: K-plane transposed (plane stride 2048B), DMA chunk-linear (R3 rule), reads 256B
//    contiguous per 16-lane phase (conflict-free, proven R7).
constexpr int A_STRIDE_B = 336;
constexpr int A_BYTES    = BM * A_STRIDE_B;        // 86016
constexpr int B_BYTES    = 20 * BN * 16;           // 40960
constexpr int LDS_BYTES  = A_BYTES + B_BYTES;      // 126976

DI unsigned short f2bf(float f) {
  union { float f; uint32_t u; } v; v.f = f;
  uint32_t r = (v.u + 0x7FFFu + ((v.u >> 16) & 1u)) >> 16;
  return (unsigned short)r;
}
DI float fast_tanh(float x) {
  float e = __expf(2.0f * x);
  return 1.0f - 2.0f / (e + 1.0f);
}
DI uint32_t swzw(uint32_t L) { return L ^ ((L >> 6) & 0x70u); }

#define GLOAD_LDS16(g, l)                                                        \
  __builtin_amdgcn_global_load_lds((const __attribute__((address_space(1))) void*)(g), \
                                   (__attribute__((address_space(3))) void*)(l), 16, 0, 0)

// ---------------- pack base_weight + spline_weight -> bf16 W[o][k], k = i*20 + t ----------------
__global__ __launch_bounds__(256) void kpack(const float* __restrict__ bw,
                                             const float* __restrict__ sw,
                                             unsigned short* __restrict__ Wb) {
  int idx = blockIdx.x * 256 + threadIdx.x;
  const float* s = sw + (size_t)idx * 19;
  unsigned short* d = Wb + (size_t)idx * 20;
  d[0] = f2bf(bw[idx]);
#pragma unroll
  for (int c = 0; c < 19; ++c) d[1 + c] = f2bf(s[c]);
}

// ---------------- fused KAN GEMM: h = tanh(A(x) @ W^T), 8 waves, wave tile 64x64 ----------------
__global__ __launch_bounds__(512, 2) void kgemm1(const float* __restrict__ z,
                                                 const float* __restrict__ ms,
                                                 const float* __restrict__ md,
                                                 const unsigned short* __restrict__ Wb,
                                                 unsigned short* __restrict__ hout) {
  extern __shared__ char ldsbuf[];
  char* AsB = ldsbuf;                         // 256 rows x 336B
  char* BsB = ldsbuf + A_BYTES;               // 20 planes x 128 rows x 16B

  const int tid  = threadIdx.x;
  const int lane = tid & 63;
  const int wv   = tid >> 6;                  // 0..7
  const int wr   = wv >> 1;                   // 0..3 : M strip (64 rows)
  const int wc   = wv & 1;                    // 0..1 : N strip (64 cols)
  const int l16  = lane & 15;
  const int lhi  = lane >> 4;

  // XCD-aware bijective swizzle: grid 512 = 8 XCD * 64
  int wg = blockIdx.x;
  int id = (wg & 7) * 64 + (wg >> 3);
  const int mblk = id & 127;
  const int nblk = id >> 7;
  const int row0 = mblk * BM;
  const int col0 = nblk * BN;

  // B DMA precompute: chunk cl = rr*512 + tid -> plane = rr*4 + (tid>>7), row = tid&127
  const unsigned short* gW0 = Wb + (size_t)(col0 + (tid & 127)) * KTOT + (tid >> 7) * 8;
  const uint32_t dma_l = (uint32_t)tid * 16u;

  // A-gen: isl constant per thread; 4 rows (r*64 apart) per thread
  const int isl = tid & 7;
  const uint32_t abase0 = (uint32_t)(tid >> 3) * A_STRIDE_B + (uint32_t)isl * 40u;

  // fragment read bases
  const uint32_t rA = (uint32_t)(wr * 64 + l16) * A_STRIDE_B + (uint32_t)lhi * 16u;
  const uint32_t rB = (uint32_t)lhi * 2048u + (uint32_t)(wc * 64 + l16) * 16u;

  f32x4 acc[4][4] = {};

  // x prefetch registers (static 4-step unroll, no dynamic indexing)
  float xv0, xv1, xv2, xv3;
  {
    int i = isl;                              // s = 0
    const float* xcol = z + i;                // i < 8 -> always z
#pragma unroll
    for (int r = 0; r < 4; ++r) {
      float v = xcol[(size_t)(row0 + (tid >> 3) + r * 64) * 128];
      if (r == 0) xv0 = v; else if (r == 1) xv1 = v; else if (r == 2) xv2 = v; else xv3 = v;
    }
  }

  for (int s = 0; s < NSTEP; ++s) {
    // ---- stage B: 5 chunks/thread, K-plane layout, linear LDS dest, full waves active
    const unsigned short* g = gW0 + s * BK;
#pragma unroll
    for (int rr = 0; rr < 5; ++rr)
      GLOAD_LDS16(g + rr * 32, BsB + dma_l + rr * 8192u);

    // ---- stage A: 4 tasks/thread; branch-free packed 40B build + 5 x ds_write_b64
#pragma unroll
    for (int r = 0; r < 4; ++r) {
      float x = (r == 0) ? xv0 : (r == 1) ? xv1 : (r == 2) ? xv2 : xv3;
      float xt = fast_tanh(x);
      float tt = (xt + 1.0f) * 8.0f;          // in [0,16]
      int   m  = (int)tt; m = m > 16 ? 16 : m;
      float u  = tt - (float)m;
      float omu = 1.0f - u;
      float u2 = u * u, u3 = u2 * u;
      float w0 = omu * omu * omu * (1.0f / 6.0f);
      float w1 = (3.0f * u3 - 6.0f * u2 + 4.0f) * (1.0f / 6.0f);
      float w2 = (-3.0f * u3 + 3.0f * u2 + 3.0f * u + 1.0f) * (1.0f / 6.0f);
      float w3 = u3 * (1.0f / 6.0f);
      float sil = xt / (1.0f + __expf(-xt));
      // bf16 pack: nonzeros at positions p = m+1..m+4 (p=1+c), word j covers p=2j,2j+1
      uint32_t b0 = f2bf(w0), b1 = f2bf(w1), b2 = f2bf(w2), b3 = f2bf(w3);
      uint32_t bs = f2bf(sil);
      uint32_t P01 = b0 | (b1 << 16), P23 = b2 | (b3 << 16);
      uint32_t Q0 = b0 << 16, Q12 = b1 | (b2 << 16), Q3 = b3;
      int odd = m & 1;
      uint32_t c0 = odd ? P01 : Q0;
      uint32_t c1 = odd ? P23 : Q12;
      uint32_t c2 = odd ? 0u : Q3;
      int jb = (m >> 1) + odd;
      uint32_t wd[10];
#pragma unroll
      for (int j = 0; j < 10; ++j)
        wd[j] = (j == jb) ? c0 : (j == jb + 1) ? c1 : (j == jb + 2) ? c2 : 0u;
      wd[0] |= bs;                            // p=0 = silu (chain leaves lo16 of word0 zero)
      uint32_t base = abase0 + (uint32_t)r * (64u * A_STRIDE_B);
#pragma unroll
      for (int zz = 0; zz < 5; ++zz) {
        uint64_t q = (uint64_t)wd[2 * zz] | ((uint64_t)wd[2 * zz + 1] << 32);
        *(uint64_t*)(AsB + base + zz * 8) = q;
      }
    }

    // ---- prefetch x for step s+1 (issues before barrier, consumed next iteration)
    float xn0 = 0.f, xn1 = 0.f, xn2 = 0.f, xn3 = 0.f;
    if (s + 1 < NSTEP) {
      int i = (s + 1) * 8 + isl;
      const float* src = (i < 128) ? z : (i < 256 ? ms : md);
      const float* xcol = src + (i & 127);
      xn0 = xcol[(size_t)(row0 + (tid >> 3)) * 128];
      xn1 = xcol[(size_t)(row0 + (tid >> 3) + 64) * 128];
      xn2 = xcol[(size_t)(row0 + (tid >> 3) + 128) * 128];
      xn3 = xcol[(size_t)(row0 + (tid >> 3) + 192) * 128];
    }

    __syncthreads();                          // drains vmcnt (DMA + x prefetch) + lgkm
    // ---- compute: 5 K-sub-steps of 32; wave tile 64x64
#pragma unroll
    for (int ks = 0; ks < 5; ++ks) {
      bf16x8 af[4], bfr[4];
#pragma unroll
      for (int mi = 0; mi < 4; ++mi)
        af[mi] = *(const bf16x8*)(AsB + rA + (uint32_t)(mi * 16) * A_STRIDE_B + ks * 64u);
#pragma unroll
      for (int ni = 0; ni < 4; ++ni)
        bfr[ni] = *(const bf16x8*)(BsB + rB + (uint32_t)ks * 8192u + (uint32_t)ni * 256u);
#pragma unroll
      for (int mi = 0; mi < 4; ++mi)
#pragma unroll
        for (int ni = 0; ni < 4; ++ni)
          acc[mi][ni] = __builtin_amdgcn_mfma_f32_16x16x32_bf16(af[mi], bfr[ni], acc[mi][ni], 0, 0, 0);
    }
    __syncthreads();                          // protect LDS from next stage overwrite

    xv0 = xn0; xv1 = xn1; xv2 = xn2; xv3 = xn3;
  }

  // ---- epilogue: tanh -> bf16 h
#pragma unroll
  for (int mi = 0; mi < 4; ++mi)
#pragma unroll
    for (int ni = 0; ni < 4; ++ni)
#pragma unroll
      for (int rg = 0; rg < 4; ++rg) {
        int grow = row0 + wr * 64 + mi * 16 + lhi * 4 + rg;
        int gcol = col0 + wc * 64 + ni * 16 + l16;
        hout[(size_t)grow * HID + gcol] = f2bf(fast_tanh(acc[mi][ni][rg]));
      }
}

// ---------------- kfinal (MFMA): 64 rows/block, all 64 output cols ----------------
__global__ __launch_bounds__(256) void kfinal(const unsigned short* __restrict__ h,
                                              const float* __restrict__ lw,
                                              const float* __restrict__ lb,
                                              float* __restrict__ out) {
  __shared__ unsigned short Ws[64 * 512];
  char* WsB = (char*)Ws;
  const int tid  = threadIdx.x;
  const int lane = tid & 63;
  const int wv   = tid >> 6;
  const int l16  = lane & 15;
  const int lhi  = lane >> 4;
  const int row0 = blockIdx.x * 64;

#pragma unroll
  for (int it = 0; it < 16; ++it) {
    int c = it * 256 + tid;
    int r = c >> 6;
    int k8 = (c & 63) * 8;
    const float* g = lw + r * 512 + k8;
    float4 f0 = *(const float4*)g;
    float4 f1 = *(const float4*)(g + 4);
    union { unsigned short s[8]; bf16x8 v; } u;
    u.s[0] = f2bf(f0.x); u.s[1] = f2bf(f0.y); u.s[2] = f2bf(f0.z); u.s[3] = f2bf(f0.w);
    u.s[4] = f2bf(f1.x); u.s[5] = f2bf(f1.y); u.s[6] = f2bf(f1.z); u.s[7] = f2bf(f1.w);
    *(bf16x8*)(WsB + swzw((uint32_t)r * 1024u + (uint32_t)k8 * 2u)) = u.v;
  }
  __syncthreads();

  const int arow = row0 + wv * 16 + l16;
  const unsigned short* ag = h + (size_t)arow * HID + lhi * 8;
  f32x4 acc[4] = {};
#pragma unroll
  for (int ks = 0; ks < 16; ++ks) {
    bf16x8 af = *(const bf16x8*)(ag + ks * 32);
#pragma unroll
    for (int ni = 0; ni < 4; ++ni) {
      uint32_t L = (uint32_t)(ni * 16 + l16) * 1024u + (uint32_t)(ks * 64 + lhi * 16);
      bf16x8 bfr = *(const bf16x8*)(WsB + swzw(L));
      acc[ni] = __builtin_amdgcn_mfma_f32_16x16x32_bf16(af, bfr, acc[ni], 0, 0, 0);
    }
  }
#pragma unroll
  for (int ni = 0; ni < 4; ++ni) {
    int col = ni * 16 + l16;
    float bias = lb[col];
#pragma unroll
    for (int rg = 0; rg < 4; ++rg) {
      int grow = row0 + wv * 16 + lhi * 4 + rg;
      out[(size_t)grow * 64 + col] = acc[ni][rg] + bias;
    }
  }
}

extern "C" void kernel_launch(void* const* d_in, const int* in_sizes, int n_in,
                              void* d_out, int out_size, void* d_ws, size_t ws_size,
                              hipStream_t stream) {
  const float* z  = (const float*)d_in[0];
  const float* ms = (const float*)d_in[1];
  const float* md = (const float*)d_in[2];
  const float* bw = (const float*)d_in[3];
  const float* sw = (const float*)d_in[4];
  const float* lw = (const float*)d_in[5];
  const float* lb = (const float*)d_in[6];
  float* out = (float*)d_out;

  unsigned short* Wb = (unsigned short*)d_ws;                        // 7.5 MiB bf16 W [512][7680]
  unsigned short* hb = (unsigned short*)((char*)d_ws + (8u << 20));  // 32 MiB bf16 h [32768][512]

  hipFuncSetAttribute((const void*)kgemm1,
                      hipFuncAttributeMaxDynamicSharedMemorySize, LDS_BYTES);

  kpack<<<(HID * IN_DIM) / 256, 256, 0, stream>>>(bw, sw, Wb);
  kgemm1<<<512, 512, LDS_BYTES, stream>>>(z, ms, md, Wb, hb);
  kfinal<<<32768 / 64, 256, 0, stream>>>(hb, lw, lb, out);
}

// Round 9
// 472.855 us; speedup vs baseline: 1.0946x; 1.0946x over previous
//
#include <hip/hip_runtime.h>
#include <hip/hip_bf16.h>
#include <cstdint>

#define DI __device__ __forceinline__

using bf16x8 = __attribute__((ext_vector_type(8))) short;
using f32x4  = __attribute__((ext_vector_type(4))) float;

constexpr int IN_DIM = 384;
constexpr int HID    = 512;
constexpr int KTOT   = IN_DIM * 20;          // 7680: k = i*20 + t
constexpr int BM = 128, BN = 128, BK = 160;  // 8 input dims per K-step
constexpr int NSTEP = KTOT / BK;             // 48
// A: row-major stride 320 (=BK*2, no pad) + bijective XOR swizzle addr^=(row&7)<<4
//    applied AFTER full address sum on BOTH write and read sides (plain ds_write path).
//    Read phases: slot = ((4row+C)%8)^(row&7) covers all 8 16B slots -> conflict-free.
// B: K-plane transposed (plane stride 2048B), DMA chunk-linear (R3 rule), reads 256B
//    contiguous per 16-lane phase (conflict-free, proven R7).
// Total 40960+40960 = 81920B -> exactly TWO blocks per CU (163840 = 160KiB) so the two
// blocks' stage/compute phases interleave (attacks the R5-R8 serialization bound).
constexpr int A_STRIDE_B = 320;
constexpr int A_BYTES    = BM * A_STRIDE_B;        // 40960
constexpr int B_BYTES    = 20 * BN * 16;           // 40960
constexpr int LDS_BYTES  = A_BYTES + B_BYTES;      // 81920

DI unsigned short f2bf(float f) {
  union { float f; uint32_t u; } v; v.f = f;
  uint32_t r = (v.u + 0x7FFFu + ((v.u >> 16) & 1u)) >> 16;
  return (unsigned short)r;
}
DI float fast_tanh(float x) {
  float e = __expf(2.0f * x);
  return 1.0f - 2.0f / (e + 1.0f);
}
DI uint32_t swzw(uint32_t L) { return L ^ ((L >> 6) & 0x70u); }

#define GLOAD_LDS16(g, l)                                                        \
  __builtin_amdgcn_global_load_lds((const __attribute__((address_space(1))) void*)(g), \
                                   (__attribute__((address_space(3))) void*)(l), 16, 0, 0)

// ---------------- pack base_weight + spline_weight -> bf16 W[o][k], k = i*20 + t ----------------
__global__ __launch_bounds__(256) void kpack(const float* __restrict__ bw,
                                             const float* __restrict__ sw,
                                             unsigned short* __restrict__ Wb) {
  int idx = blockIdx.x * 256 + threadIdx.x;
  const float* s = sw + (size_t)idx * 19;
  unsigned short* d = Wb + (size_t)idx * 20;
  d[0] = f2bf(bw[idx]);
#pragma unroll
  for (int c = 0; c < 19; ++c) d[1 + c] = f2bf(s[c]);
}

// ---------------- fused KAN GEMM: h = tanh(A(x) @ W^T), 4 waves, wave tile 64x64 ----------------
__global__ __launch_bounds__(256, 2) void kgemm1(const float* __restrict__ z,
                                                 const float* __restrict__ ms,
                                                 const float* __restrict__ md,
                                                 const unsigned short* __restrict__ Wb,
                                                 unsigned short* __restrict__ hout) {
  extern __shared__ char ldsbuf[];
  char* AsB = ldsbuf;                         // 128 rows x 320B, XOR-swizzled
  char* BsB = ldsbuf + A_BYTES;               // 20 planes x 128 rows x 16B

  const int tid  = threadIdx.x;
  const int lane = tid & 63;
  const int wv   = tid >> 6;                  // 0..3
  const int wr   = wv >> 1;                   // 0..1 : M strip (64 rows)
  const int wc   = wv & 1;                    // 0..1 : N strip (64 cols)
  const int l16  = lane & 15;
  const int lhi  = lane >> 4;

  // XCD-aware bijective swizzle: grid 1024 = 8 XCD * 128
  int wg = blockIdx.x;
  int id = (wg & 7) * 128 + (wg >> 3);
  const int mblk = id & 255;
  const int nblk = id >> 8;
  const int row0 = mblk * BM;
  const int col0 = nblk * BN;

  // B DMA precompute: chunk cl = rr*256 + tid -> plane = rr*2 + (tid>>7), row = tid&127
  const unsigned short* gW0 = Wb + (size_t)(col0 + (tid & 127)) * KTOT + (tid >> 7) * 8;
  const uint32_t dma_l = (uint32_t)tid * 16u;

  // A-gen: isl constant per thread; 4 rows (r*32 apart) per thread
  const int isl = tid & 7;
  const int arow0 = tid >> 3;                 // 0..31

  // fragment read bases (A XOR applied per access after full sum; f const per lane)
  const uint32_t fA = (uint32_t)(l16 & 7) << 4;   // row = wr*64+mi*16+l16 -> row&7 = l16&7
  const uint32_t rA = (uint32_t)(wr * 64 + l16) * A_STRIDE_B + (uint32_t)lhi * 16u;
  const uint32_t rB = (uint32_t)lhi * 2048u + (uint32_t)(wc * 64 + l16) * 16u;

  f32x4 acc[4][4] = {};

  // x prefetch registers
  float xv0, xv1, xv2, xv3;
  {
    const float* xcol = z + isl;              // s=0 -> i = isl < 128 -> z
    xv0 = xcol[(size_t)(row0 + arow0) * 128];
    xv1 = xcol[(size_t)(row0 + arow0 + 32) * 128];
    xv2 = xcol[(size_t)(row0 + arow0 + 64) * 128];
    xv3 = xcol[(size_t)(row0 + arow0 + 96) * 128];
  }

  for (int s = 0; s < NSTEP; ++s) {
    // ---- stage B: 10 chunks/thread, K-plane layout, linear LDS dest
    const unsigned short* g = gW0 + s * BK;
#pragma unroll
    for (int rr = 0; rr < 10; ++rr)
      GLOAD_LDS16(g + rr * 16, BsB + dma_l + rr * 4096u);

    // ---- stage A: 4 tasks/thread; packed 40B build (R8-proven) + 5 x ds_write_b64
#pragma unroll
    for (int r = 0; r < 4; ++r) {
      float x = (r == 0) ? xv0 : (r == 1) ? xv1 : (r == 2) ? xv2 : xv3;
      int arow = arow0 + r * 32;
      float xt = fast_tanh(x);
      float tt = (xt + 1.0f) * 8.0f;          // in [0,16]
      int   m  = (int)tt; m = m > 16 ? 16 : m;
      float u  = tt - (float)m;
      float omu = 1.0f - u;
      float u2 = u * u, u3 = u2 * u;
      float w0 = omu * omu * omu * (1.0f / 6.0f);
      float w1 = (3.0f * u3 - 6.0f * u2 + 4.0f) * (1.0f / 6.0f);
      float w2 = (-3.0f * u3 + 3.0f * u2 + 3.0f * u + 1.0f) * (1.0f / 6.0f);
      float w3 = u3 * (1.0f / 6.0f);
      float sil = xt / (1.0f + __expf(-xt));
      uint32_t b0 = f2bf(w0), b1 = f2bf(w1), b2 = f2bf(w2), b3 = f2bf(w3);
      uint32_t bs = f2bf(sil);
      uint32_t P01 = b0 | (b1 << 16), P23 = b2 | (b3 << 16);
      uint32_t Q0 = b0 << 16, Q12 = b1 | (b2 << 16), Q3 = b3;
      int odd = m & 1;
      uint32_t c0 = odd ? P01 : Q0;
      uint32_t c1 = odd ? P23 : Q12;
      uint32_t c2 = odd ? 0u : Q3;
      int jb = (m >> 1) + odd;
      uint32_t wd[10];
#pragma unroll
      for (int j = 0; j < 10; ++j)
        wd[j] = (j == jb) ? c0 : (j == jb + 1) ? c1 : (j == jb + 2) ? c2 : 0u;
      wd[0] |= bs;                            // p=0 = silu
      uint32_t base = (uint32_t)arow * A_STRIDE_B + (uint32_t)isl * 40u;
      uint32_t fw = ((uint32_t)arow & 7u) << 4;
#pragma unroll
      for (int zz = 0; zz < 5; ++zz) {
        uint64_t q = (uint64_t)wd[2 * zz] | ((uint64_t)wd[2 * zz + 1] << 32);
        *(uint64_t*)(AsB + ((base + zz * 8) ^ fw)) = q;
      }
    }

    // ---- prefetch x for step s+1
    float xn0 = 0.f, xn1 = 0.f, xn2 = 0.f, xn3 = 0.f;
    if (s + 1 < NSTEP) {
      int i = (s + 1) * 8 + isl;
      const float* src = (i < 128) ? z : (i < 256 ? ms : md);
      const float* xcol = src + (i & 127);
      xn0 = xcol[(size_t)(row0 + arow0) * 128];
      xn1 = xcol[(size_t)(row0 + arow0 + 32) * 128];
      xn2 = xcol[(size_t)(row0 + arow0 + 64) * 128];
      xn3 = xcol[(size_t)(row0 + arow0 + 96) * 128];
    }

    __syncthreads();                          // drains vmcnt (DMA + x) + lgkm (A writes)
    // ---- compute: 5 K-sub-steps of 32; wave tile 64x64
#pragma unroll
    for (int ks = 0; ks < 5; ++ks) {
      bf16x8 af[4], bfr[4];
#pragma unroll
      for (int mi = 0; mi < 4; ++mi)
        af[mi] = *(const bf16x8*)(AsB + ((rA + (uint32_t)(mi * 16) * A_STRIDE_B + ks * 64u) ^ fA));
#pragma unroll
      for (int ni = 0; ni < 4; ++ni)
        bfr[ni] = *(const bf16x8*)(BsB + rB + (uint32_t)ks * 8192u + (uint32_t)ni * 256u);
#pragma unroll
      for (int mi = 0; mi < 4; ++mi)
#pragma unroll
        for (int ni = 0; ni < 4; ++ni)
          acc[mi][ni] = __builtin_amdgcn_mfma_f32_16x16x32_bf16(af[mi], bfr[ni], acc[mi][ni], 0, 0, 0);
    }
    __syncthreads();                          // protect LDS from next stage overwrite

    xv0 = xn0; xv1 = xn1; xv2 = xn2; xv3 = xn3;
  }

  // ---- epilogue: tanh -> bf16 h
#pragma unroll
  for (int mi = 0; mi < 4; ++mi)
#pragma unroll
    for (int ni = 0; ni < 4; ++ni)
#pragma unroll
      for (int rg = 0; rg < 4; ++rg) {
        int grow = row0 + wr * 64 + mi * 16 + lhi * 4 + rg;
        int gcol = col0 + wc * 64 + ni * 16 + l16;
        hout[(size_t)grow * HID + gcol] = f2bf(fast_tanh(acc[mi][ni][rg]));
      }
}

// ---------------- kfinal (MFMA): 64 rows/block, all 64 output cols ----------------
__global__ __launch_bounds__(256) void kfinal(const unsigned short* __restrict__ h,
                                              const float* __restrict__ lw,
                                              const float* __restrict__ lb,
                                              float* __restrict__ out) {
  __shared__ unsigned short Ws[64 * 512];
  char* WsB = (char*)Ws;
  const int tid  = threadIdx.x;
  const int lane = tid & 63;
  const int wv   = tid >> 6;
  const int l16  = lane & 15;
  const int lhi  = lane >> 4;
  const int row0 = blockIdx.x * 64;

#pragma unroll
  for (int it = 0; it < 16; ++it) {
    int c = it * 256 + tid;
    int r = c >> 6;
    int k8 = (c & 63) * 8;
    const float* g = lw + r * 512 + k8;
    float4 f0 = *(const float4*)g;
    float4 f1 = *(const float4*)(g + 4);
    union { unsigned short s[8]; bf16x8 v; } u;
    u.s[0] = f2bf(f0.x); u.s[1] = f2bf(f0.y); u.s[2] = f2bf(f0.z); u.s[3] = f2bf(f0.w);
    u.s[4] = f2bf(f1.x); u.s[5] = f2bf(f1.y); u.s[6] = f2bf(f1.z); u.s[7] = f2bf(f1.w);
    *(bf16x8*)(WsB + swzw((uint32_t)r * 1024u + (uint32_t)k8 * 2u)) = u.v;
  }
  __syncthreads();

  const int arow = row0 + wv * 16 + l16;
  const unsigned short* ag = h + (size_t)arow * HID + lhi * 8;
  f32x4 acc[4] = {};
#pragma unroll
  for (int ks = 0; ks < 16; ++ks) {
    bf16x8 af = *(const bf16x8*)(ag + ks * 32);
#pragma unroll
    for (int ni = 0; ni < 4; ++ni) {
      uint32_t L = (uint32_t)(ni * 16 + l16) * 1024u + (uint32_t)(ks * 64 + lhi * 16);
      bf16x8 bfr = *(const bf16x8*)(WsB + swzw(L));
      acc[ni] = __builtin_amdgcn_mfma_f32_16x16x32_bf16(af, bfr, acc[ni], 0, 0, 0);
    }
  }
#pragma unroll
  for (int ni = 0; ni < 4; ++ni) {
    int col = ni * 16 + l16;
    float bias = lb[col];
#pragma unroll
    for (int rg = 0; rg < 4; ++rg) {
      int grow = row0 + wv * 16 + lhi * 4 + rg;
      out[(size_t)grow * 64 + col] = acc[ni][rg] + bias;
    }
  }
}

extern "C" void kernel_launch(void* const* d_in, const int* in_sizes, int n_in,
                              void* d_out, int out_size, void* d_ws, size_t ws_size,
                              hipStream_t stream) {
  const float* z  = (const float*)d_in[0];
  const float* ms = (const float*)d_in[1];
  const float* md = (const float*)d_in[2];
  const float* bw = (const float*)d_in[3];
  const float* sw = (const float*)d_in[4];
  const float* lw = (const float*)d_in[5];
  const float* lb = (const float*)d_in[6];
  float* out = (float*)d_out;

  unsigned short* Wb = (unsigned short*)d_ws;                        // 7.5 MiB bf16 W [512][7680]
  unsigned short* hb = (unsigned short*)((char*)d_ws + (8u << 20));  // 32 MiB bf16 h [32768][512]

  hipFuncSetAttribute((const void*)kgemm1,
                      hipFuncAttributeMaxDynamicSharedMemorySize, LDS_BYTES);

  kpack<<<(HID * IN_DIM) / 256, 256, 0, stream>>>(bw, sw, Wb);
  kgemm1<<<1024, 256, LDS_BYTES, stream>>>(z, ms, md, Wb, hb);
  kfinal<<<32768 / 64, 256, 0, stream>>>(hb, lw, lb, out);
}